// Round 4
// baseline (503.696 us; speedup 1.0000x reference)
//
#include <hip/hip_runtime.h>

typedef unsigned short u16;
typedef unsigned char u8;
typedef __attribute__((ext_vector_type(8))) u16 u16x8;
typedef __attribute__((ext_vector_type(8))) __bf16 bf16x8;
typedef __attribute__((ext_vector_type(4))) float f32x4;

#define NN 8192
#define FIN 256
#define FOUT 128

__device__ __forceinline__ u16 f2bf(float f) {       // RNE
  unsigned u = __float_as_uint(f);
  u += 0x7fffu + ((u >> 16) & 1u);
  return (u16)(u >> 16);
}
__device__ __forceinline__ u16 f2bft(float f) {      // truncate
  return (u16)(__float_as_uint(f) >> 16);
}
__device__ __forceinline__ float bf2f(u16 s) {
  return __uint_as_float(((unsigned)s) << 16);
}

// ---------------- kernel 0: W -> bf16 hi/lo split ----------------
__global__ __launch_bounds__(256) void k_splitw(const float* __restrict__ W,
                                                u16* __restrict__ Whi,
                                                u16* __restrict__ Wlo) {
  int t = blockIdx.x * 256 + threadIdx.x;
  float w = W[t];
  u16 hi = f2bf(w);
  Whi[t] = hi;
  Wlo[t] = f2bf(w - bf2f(hi));
}

// ---------------- kernel A: adj -> bitmask (globally sequential sweep) --------
// 1024 blocks x 256 thr = 4096 waves; 131072 chunks of 512 cols (2 KB adj).
// g = wave_id + iter*4096: concurrent waves cover one contiguous 8 MB window.
__global__ __launch_bounds__(256) void k_mask(const int* __restrict__ adj,
                                              u8* __restrict__ mask) {
  const int wave_id = blockIdx.x * 4 + (threadIdx.x >> 6);
  const int l = threadIdx.x & 63;
#pragma unroll 1
  for (int it = 0; it < 32; ++it) {
    int g = wave_id + it * 4096;
    int row = g >> 4, cir = g & 15;
    const int* p = adj + (size_t)row * NN + cir * 512 + l * 8;
    int4 a = *(const int4*)p;
    int4 b = *(const int4*)(p + 4);
    unsigned m = 0;
    m |= min((unsigned)a.x, 1u);
    m |= min((unsigned)a.y, 1u) << 1;
    m |= min((unsigned)a.z, 1u) << 2;
    m |= min((unsigned)a.w, 1u) << 3;
    m |= min((unsigned)b.x, 1u) << 4;
    m |= min((unsigned)b.y, 1u) << 5;
    m |= min((unsigned)b.z, 1u) << 6;
    m |= min((unsigned)b.w, 1u) << 7;
    mask[(size_t)row * 1024 + cir * 64 + l] = (u8)m;
  }
}

// ---------------- kernel 1: Xp, tables, swizzled bf16 Xp, diag weights ----------
__global__ __launch_bounds__(256) void k_xp(const float* __restrict__ X,
    const u16* __restrict__ Whi, const u16* __restrict__ Wlo,
    const float* __restrict__ bias, const float* __restrict__ S,
    const int* __restrict__ adj,
    u16* __restrict__ Bsw, float* __restrict__ cexpA,
    u16* __restrict__ jebA, u16* __restrict__ jeb2A, float* __restrict__ diagW) {
  __shared__ float Xs[16 * 260];
  __shared__ float Xp[16 * 132];
  __shared__ float Ss[256];
  const int tid = threadIdx.x;
  const int i0 = blockIdx.x * 16;
  Ss[tid] = S[tid];
  {
    int r = tid >> 4, c = (tid & 15) * 16;
    const float* src = X + (size_t)(i0 + r) * FIN + c;
    float* dst = Xs + r * 260 + c;
#pragma unroll
    for (int k = 0; k < 16; k += 4) *(float4*)(dst + k) = *(const float4*)(src + k);
  }
  __syncthreads();

  const int w = tid >> 6, l = tid & 63, li = l & 15, quad = l >> 4;
  f32x4 acc[2];
  acc[0] = f32x4{0.f, 0.f, 0.f, 0.f};
  acc[1] = f32x4{0.f, 0.f, 0.f, 0.f};
  for (int k0 = 0; k0 < FIN; k0 += 32) {
    const float* xp = Xs + li * 260 + k0 + quad * 8;
    float4 xa = *(const float4*)xp;
    float4 xb = *(const float4*)(xp + 4);
    float xv[8] = {xa.x, xa.y, xa.z, xa.w, xb.x, xb.y, xb.z, xb.w};
    u16x8 ahiu, alou;
#pragma unroll
    for (int jj = 0; jj < 8; ++jj) {
      u16 h = f2bf(xv[jj]);
      ahiu[jj] = h;
      alou[jj] = f2bf(xv[jj] - bf2f(h));
    }
    bf16x8 ahi = __builtin_bit_cast(bf16x8, ahiu);
    bf16x8 alo = __builtin_bit_cast(bf16x8, alou);
#pragma unroll
    for (int t2 = 0; t2 < 2; ++t2) {
      int f = (w * 2 + t2) * 16 + li;
      size_t wofs = (size_t)f * FIN + k0 + quad * 8;
      bf16x8 bhi = __builtin_bit_cast(bf16x8, *(const u16x8*)(Whi + wofs));
      bf16x8 blo = __builtin_bit_cast(bf16x8, *(const u16x8*)(Wlo + wofs));
      acc[t2] = __builtin_amdgcn_mfma_f32_16x16x32_bf16(ahi, bhi, acc[t2], 0, 0, 0);
      acc[t2] = __builtin_amdgcn_mfma_f32_16x16x32_bf16(alo, bhi, acc[t2], 0, 0, 0);
      acc[t2] = __builtin_amdgcn_mfma_f32_16x16x32_bf16(ahi, blo, acc[t2], 0, 0, 0);
    }
  }
#pragma unroll
  for (int t2 = 0; t2 < 2; ++t2) {
    int f = (w * 2 + t2) * 16 + li;
    float bv = bias[f];
#pragma unroll
    for (int r = 0; r < 4; ++r)
      Xp[(quad * 4 + r) * 132 + f] = acc[t2][r] + bv;
  }
  __syncthreads();

  {
    int li2 = tid & 15, q2sub = (tid >> 4) & 1, nt = tid >> 5;
    int f = nt * 16 + li2;
    int rb = q2sub * 8;
    int q2 = ((i0 & 16) >> 3) + q2sub;
    u16x8 ou;
#pragma unroll
    for (int jj = 0; jj < 8; ++jj) ou[jj] = f2bf(Xp[(rb + jj) * 132 + f]);
    *(u16x8*)(Bsw + ((size_t)(i0 >> 5) * 8 + nt) * 512 + (size_t)(q2 * 16 + li2) * 8) = ou;
  }

  {
    int r = tid >> 4, sub = tid & 15;
    float pa = 0.f, pb = 0.f;
#pragma unroll
    for (int m = 0; m < 8; ++m) {
      float x = Xp[r * 132 + sub + m * 16];
      pa += x * Ss[sub + m * 16];
      pb += x * Ss[128 + sub + m * 16];
    }
    pa += __shfl_xor(pa, 1); pa += __shfl_xor(pa, 2);
    pa += __shfl_xor(pa, 4); pa += __shfl_xor(pa, 8);
    pb += __shfl_xor(pb, 1); pb += __shfl_xor(pb, 2);
    pb += __shfl_xor(pb, 4); pb += __shfl_xor(pb, 8);
    if (sub == 0) {
      int i = i0 + r;
      float cc = expf(-0.99f * pa);
      u16 ebq = f2bf(expf(pb));
      u16 e2q = f2bf(expf(0.01f * pb));
      cexpA[i] = cc;
      jebA[i] = ebq;
      jeb2A[i] = e2q;
      float wii = fmaxf(bf2f(ebq), cc * bf2f(e2q));
      float wq = bf2f(f2bft(wii));
      int ad = adj[(size_t)i * NN + i];
      diagW[i] = (ad != 0) ? 0.f : wq;
    }
  }
}

// ---------------- kernel 2: masked softmax-weighted aggregation ----------------
// 256 blocks x 32 rows, 8 waves; wave owns a 1024-col K-chunk (32 ksteps),
// 2 row-groups of 16. Barrier-free K-loop; adj via 8 MB bitmask.
__global__ __launch_bounds__(512, 3) void k_gat(const u8* __restrict__ mask,
    const u16* __restrict__ Bsw, const float* __restrict__ cexpA,
    const u16* __restrict__ jebA, const u16* __restrict__ jeb2A,
    const float* __restrict__ diagW, float* __restrict__ out) {
  __shared__ float sacc[32 * 132];
  __shared__ float sden[32];
  const int tid = threadIdx.x;
  const int i0 = blockIdx.x * 32;

  // ---- init accumulators with the diagonal (eye-mask) contribution ----
  {
    int r = tid >> 4, f8 = (tid & 15) * 8;
    int i = i0 + r;
    float dw = diagW[i];
    int jblk = i >> 5, q2 = (i & 31) >> 3, jj = i & 7;
#pragma unroll
    for (int k = 0; k < 8; ++k) {
      int ff = f8 + k;
      u16 xb = Bsw[((size_t)jblk * 8 + (ff >> 4)) * 512 +
                   (size_t)(q2 * 16 + (ff & 15)) * 8 + jj];
      sacc[r * 132 + ff] = dw * bf2f(xb);
    }
    if (tid < 32) sden[tid] = diagW[i0 + tid];
  }
  __syncthreads();

  const int w = tid >> 6, l = tid & 63, li = l & 15, quad = l >> 4;
  const float c0 = cexpA[i0 + li];
  const float c1 = cexpA[i0 + 16 + li];
  const u8* mp0 = mask + (size_t)(i0 + li) * 1024;
  const u8* mp1 = mp0 + 16 * 1024;

  f32x4 acc0[8], acc1[8];
#pragma unroll
  for (int nt = 0; nt < 8; ++nt) {
    acc0[nt] = f32x4{0.f, 0.f, 0.f, 0.f};
    acc1[nt] = f32x4{0.f, 0.f, 0.f, 0.f};
  }
  f32x4 accD0 = f32x4{0.f, 0.f, 0.f, 0.f};
  f32x4 accD1 = f32x4{0.f, 0.f, 0.f, 0.f};
  u16x8 onesu;
#pragma unroll
  for (int jj = 0; jj < 8; ++jj) onesu[jj] = 0x3F80;
  const bf16x8 ONES = __builtin_bit_cast(bf16x8, onesu);

  const int ks0 = w * 32;   // global kstep base: cols [w*1024, w*1024+1024)
  for (int s = 0; s < 32; ++s) {
    const int ks = ks0 + s;
    const int jq = ks * 32 + quad * 8;
    int mb0 = mp0[ks * 4 + quad];
    int mb1 = mp1[ks * 4 + quad];
    u16x8 ceb = *(const u16x8*)(jebA + jq);
    u16x8 ce2 = *(const u16x8*)(jeb2A + jq);
    float w0[8], w1[8];
#pragma unroll
    for (int e = 0; e < 8; ++e) {
      float eb = bf2f(ceb[e]);
      float e2 = bf2f(ce2[e]);
      float a0 = fmaxf(eb, c0 * e2);
      float a1 = fmaxf(eb, c1 * e2);
      w0[e] = ((mb0 >> e) & 1) ? a0 : 0.f;
      w1[e] = ((mb1 >> e) & 1) ? a1 : 0.f;
    }
    unsigned p0[4], p1[4];
#pragma unroll
    for (int p = 0; p < 4; ++p) {
      p0[p] = __builtin_amdgcn_perm(__float_as_uint(w0[2 * p + 1]),
                                    __float_as_uint(w0[2 * p]), 0x07060302u);
      p1[p] = __builtin_amdgcn_perm(__float_as_uint(w1[2 * p + 1]),
                                    __float_as_uint(w1[2 * p]), 0x07060302u);
    }
    bf16x8 A0 = __builtin_bit_cast(bf16x8, *(u16x8*)p0);
    bf16x8 A1 = __builtin_bit_cast(bf16x8, *(u16x8*)p1);

    const u16* bb = Bsw + (size_t)ks * 4096 + (size_t)l * 8;
#pragma unroll
    for (int nt = 0; nt < 8; ++nt) {
      bf16x8 B = __builtin_bit_cast(bf16x8, *(const u16x8*)(bb + nt * 512));
      acc0[nt] = __builtin_amdgcn_mfma_f32_16x16x32_bf16(A0, B, acc0[nt], 0, 0, 0);
      acc1[nt] = __builtin_amdgcn_mfma_f32_16x16x32_bf16(A1, B, acc1[nt], 0, 0, 0);
    }
    accD0 = __builtin_amdgcn_mfma_f32_16x16x32_bf16(A0, ONES, accD0, 0, 0, 0);
    accD1 = __builtin_amdgcn_mfma_f32_16x16x32_bf16(A1, ONES, accD1, 0, 0, 0);
  }

  // ---- reduce across waves ----
  if (li == 0) {
#pragma unroll
    for (int r = 0; r < 4; ++r) {
      atomicAdd(&sden[quad * 4 + r], accD0[r]);
      atomicAdd(&sden[16 + quad * 4 + r], accD1[r]);
    }
  }
#pragma unroll
  for (int nt = 0; nt < 8; ++nt) {
#pragma unroll
    for (int r = 0; r < 4; ++r) {
      atomicAdd(&sacc[(quad * 4 + r) * 132 + nt * 16 + li], acc0[nt][r]);
      atomicAdd(&sacc[(16 + quad * 4 + r) * 132 + nt * 16 + li], acc1[nt][r]);
    }
  }
  __syncthreads();

  // ---- epilogue: normalize + sigmoid, coalesced float4 store ----
  {
    int r = tid >> 4, f8 = (tid & 15) * 8;
    float rd = 1.f / sden[r];
    float4 v0 = *(const float4*)&sacc[r * 132 + f8];
    float4 v1 = *(const float4*)&sacc[r * 132 + f8 + 4];
    float o[8] = {v0.x, v0.y, v0.z, v0.w, v1.x, v1.y, v1.z, v1.w};
#pragma unroll
    for (int k = 0; k < 8; ++k) {
      float t = o[k] * rd;
      o[k] = 1.f / (1.f + __expf(-t));
    }
    float* op = out + (size_t)(i0 + r) * FOUT + f8;
    *(float4*)op = make_float4(o[0], o[1], o[2], o[3]);
    *(float4*)(op + 4) = make_float4(o[4], o[5], o[6], o[7]);
  }
}

extern "C" void kernel_launch(void* const* d_in, const int* in_sizes, int n_in,
                              void* d_out, int out_size, void* d_ws, size_t ws_size,
                              hipStream_t stream) {
  const float* X = (const float*)d_in[0];
  const int* adj = (const int*)d_in[1];
  const float* W = (const float*)d_in[2];
  const float* bias = (const float*)d_in[3];
  const float* S = (const float*)d_in[4];
  float* out = (float*)d_out;

  char* ws = (char*)d_ws;
  u16* Bsw      = (u16*)(ws);                  // 2,097,152 B
  u16* Whi      = (u16*)(ws + 2097152);        //    65,536 B
  u16* Wlo      = (u16*)(ws + 2162688);        //    65,536 B
  float* cexpA  = (float*)(ws + 2228224);      //    32,768 B
  u16* jebA     = (u16*)(ws + 2260992);        //    16,384 B
  u16* jeb2A    = (u16*)(ws + 2277376);        //    16,384 B
  float* diagW  = (float*)(ws + 2293760);      //    32,768 B
  u8* mask      = (u8*)(ws + 2326528);         // 8,388,608 B -> end 10,715,136

  hipLaunchKernelGGL(k_mask, dim3(1024), dim3(256), 0, stream, adj, mask);
  hipLaunchKernelGGL(k_splitw, dim3(128), dim3(256), 0, stream, W, Whi, Wlo);
  hipLaunchKernelGGL(k_xp, dim3(512), dim3(256), 0, stream, X, Whi, Wlo, bias, S, adj,
                     Bsw, cexpA, jebA, jeb2A, diagW);
  hipLaunchKernelGGL(k_gat, dim3(256), dim3(512), 0, stream, mask, Bsw, cexpA,
                     jebA, jeb2A, diagW, out);
}

// Round 5
// 440.525 us; speedup vs baseline: 1.1434x; 1.1434x over previous
//
#include <hip/hip_runtime.h>

typedef unsigned short u16;
typedef __attribute__((ext_vector_type(8))) u16 u16x8;
typedef __attribute__((ext_vector_type(8))) __bf16 bf16x8;
typedef __attribute__((ext_vector_type(4))) float f32x4;
typedef __attribute__((ext_vector_type(4))) int i32x4;

#define NN 8192
#define FIN 256
#define FOUT 128
#define PW 512            // column panel width in k_gat
#define NP (NN / PW)      // 16 panels
#define WSTRIDE 520       // u16 per LDS weight row (512 + 8 pad)

__device__ __forceinline__ u16 f2bf(float f) {       // RNE
  unsigned u = __float_as_uint(f);
  u += 0x7fffu + ((u >> 16) & 1u);
  return (u16)(u >> 16);
}
__device__ __forceinline__ u16 f2bft(float f) {      // truncate
  return (u16)(__float_as_uint(f) >> 16);
}
__device__ __forceinline__ float bf2f(u16 s) {
  return __uint_as_float(((unsigned)s) << 16);
}
// nontemporal streaming read of 16 B (emits global_load_dwordx4 ... nt)
__device__ __forceinline__ i32x4 ntload4(const int* p) {
  return __builtin_nontemporal_load((const i32x4*)p);
}

// ---------------- kernel 0: W -> bf16 hi/lo split ----------------
__global__ __launch_bounds__(256) void k_splitw(const float* __restrict__ W,
                                                u16* __restrict__ Whi,
                                                u16* __restrict__ Wlo) {
  int t = blockIdx.x * 256 + threadIdx.x;
  float w = W[t];
  u16 hi = f2bf(w);
  Whi[t] = hi;
  Wlo[t] = f2bf(w - bf2f(hi));
}

// ---------------- kernel 1: Xp, tables, swizzled bf16 Xp, diag weights ----------
__global__ __launch_bounds__(256) void k_xp(const float* __restrict__ X,
    const u16* __restrict__ Whi, const u16* __restrict__ Wlo,
    const float* __restrict__ bias, const float* __restrict__ S,
    const int* __restrict__ adj,
    u16* __restrict__ Bsw, float* __restrict__ cexpA,
    u16* __restrict__ jebA, u16* __restrict__ jeb2A, float* __restrict__ diagW) {
  __shared__ float Xs[16 * 260];
  __shared__ float Xp[16 * 132];
  __shared__ float Ss[256];
  const int tid = threadIdx.x;
  const int i0 = blockIdx.x * 16;
  Ss[tid] = S[tid];
  {
    int r = tid >> 4, c = (tid & 15) * 16;
    const float* src = X + (size_t)(i0 + r) * FIN + c;
    float* dst = Xs + r * 260 + c;
#pragma unroll
    for (int k = 0; k < 16; k += 4) *(float4*)(dst + k) = *(const float4*)(src + k);
  }
  __syncthreads();

  const int w = tid >> 6, l = tid & 63, li = l & 15, quad = l >> 4;
  f32x4 acc[2];
  acc[0] = f32x4{0.f, 0.f, 0.f, 0.f};
  acc[1] = f32x4{0.f, 0.f, 0.f, 0.f};
  for (int k0 = 0; k0 < FIN; k0 += 32) {
    const float* xp = Xs + li * 260 + k0 + quad * 8;
    float4 xa = *(const float4*)xp;
    float4 xb = *(const float4*)(xp + 4);
    float xv[8] = {xa.x, xa.y, xa.z, xa.w, xb.x, xb.y, xb.z, xb.w};
    u16x8 ahiu, alou;
#pragma unroll
    for (int jj = 0; jj < 8; ++jj) {
      u16 h = f2bf(xv[jj]);
      ahiu[jj] = h;
      alou[jj] = f2bf(xv[jj] - bf2f(h));
    }
    bf16x8 ahi = __builtin_bit_cast(bf16x8, ahiu);
    bf16x8 alo = __builtin_bit_cast(bf16x8, alou);
#pragma unroll
    for (int t2 = 0; t2 < 2; ++t2) {
      int f = (w * 2 + t2) * 16 + li;
      size_t wofs = (size_t)f * FIN + k0 + quad * 8;
      bf16x8 bhi = __builtin_bit_cast(bf16x8, *(const u16x8*)(Whi + wofs));
      bf16x8 blo = __builtin_bit_cast(bf16x8, *(const u16x8*)(Wlo + wofs));
      acc[t2] = __builtin_amdgcn_mfma_f32_16x16x32_bf16(ahi, bhi, acc[t2], 0, 0, 0);
      acc[t2] = __builtin_amdgcn_mfma_f32_16x16x32_bf16(alo, bhi, acc[t2], 0, 0, 0);
      acc[t2] = __builtin_amdgcn_mfma_f32_16x16x32_bf16(ahi, blo, acc[t2], 0, 0, 0);
    }
  }
#pragma unroll
  for (int t2 = 0; t2 < 2; ++t2) {
    int f = (w * 2 + t2) * 16 + li;
    float bv = bias[f];
#pragma unroll
    for (int r = 0; r < 4; ++r)
      Xp[(quad * 4 + r) * 132 + f] = acc[t2][r] + bv;
  }
  __syncthreads();

  {
    int li2 = tid & 15, q2sub = (tid >> 4) & 1, nt = tid >> 5;
    int f = nt * 16 + li2;
    int rb = q2sub * 8;
    int q2 = ((i0 & 16) >> 3) + q2sub;
    u16x8 ou;
#pragma unroll
    for (int jj = 0; jj < 8; ++jj) ou[jj] = f2bf(Xp[(rb + jj) * 132 + f]);
    *(u16x8*)(Bsw + ((size_t)(i0 >> 5) * 8 + nt) * 512 + (size_t)(q2 * 16 + li2) * 8) = ou;
  }

  {
    int r = tid >> 4, sub = tid & 15;
    float pa = 0.f, pb = 0.f;
#pragma unroll
    for (int m = 0; m < 8; ++m) {
      float x = Xp[r * 132 + sub + m * 16];
      pa += x * Ss[sub + m * 16];
      pb += x * Ss[128 + sub + m * 16];
    }
    pa += __shfl_xor(pa, 1); pa += __shfl_xor(pa, 2);
    pa += __shfl_xor(pa, 4); pa += __shfl_xor(pa, 8);
    pb += __shfl_xor(pb, 1); pb += __shfl_xor(pb, 2);
    pb += __shfl_xor(pb, 4); pb += __shfl_xor(pb, 8);
    if (sub == 0) {
      int i = i0 + r;
      float cc = expf(-0.99f * pa);
      u16 ebq = f2bf(expf(pb));
      u16 e2q = f2bf(expf(0.01f * pb));
      cexpA[i] = cc;
      jebA[i] = ebq;
      jeb2A[i] = e2q;
      float wii = fmaxf(bf2f(ebq), cc * bf2f(e2q));
      float wq = bf2f(f2bft(wii));
      int ad = adj[(size_t)i * NN + i];
      diagW[i] = (ad != 0) ? 0.f : wq;
    }
  }
}

// ---------------- kernel 2: masked softmax-weighted aggregation ----------------
// 512 blocks (16 rows) x 8 waves. Column panels of 512 staged to LDS as bf16
// weights with contiguous NONTEMPORAL global reads of adj (streaming, no cache
// allocation); MFMA A-frags via ds_read_b128.
__global__ __launch_bounds__(512, 4) void k_gat(const int* __restrict__ adj,
    const u16* __restrict__ Bsw, const float* __restrict__ cexpA,
    const u16* __restrict__ jebA, const u16* __restrict__ jeb2A,
    const float* __restrict__ diagW, float* __restrict__ out) {
  __shared__ u16 wb[2][16 * WSTRIDE];     // 33,280 B
  __shared__ float sacc[16 * 132];        //  8,448 B
  __shared__ float sden[16];
  const int tid = threadIdx.x;
  const int i0 = blockIdx.x * 16;
  const int w = tid >> 6, l = tid & 63, li = l & 15, quad = l >> 4;

  // ---- init accumulators with the diagonal (eye-mask) contribution ----
  {
    int r = tid >> 5, f = (tid & 31) * 4;
    int i = i0 + r;
    float dw = diagW[i];
    size_t slotbase = (size_t)(i0 >> 5) * 8;
    int laneq = ((i & 31) >> 3) * 16;
    int elem = i & 7;
    float4 v;
    float* vp = &v.x;
#pragma unroll
    for (int k = 0; k < 4; ++k) {
      int ff = f + k;
      u16 xb = Bsw[(slotbase + (ff >> 4)) * 512 + (size_t)(laneq + (ff & 15)) * 8 + elem];
      vp[k] = dw * bf2f(xb);
    }
    *(float4*)&sacc[r * 132 + f] = v;
    if (tid < 16) sden[tid] = diagW[i0 + tid];
  }

  // ---- staging constants: this wave stages rows 2w, 2w+1 ----
  const int r0 = 2 * w;
  const float c0 = cexpA[i0 + r0];
  const float c1 = cexpA[i0 + r0 + 1];
  const int* arow0 = adj + (size_t)(i0 + r0) * NN;
  const int* arow1 = arow0 + NN;

  i32x4 pa[4];            // [row2*2 + chunk]
  ushort4 teb[2], te2[2];

  auto stage_load = [&](int p) {
    int base = p * PW + l * 4;
#pragma unroll
    for (int k = 0; k < 2; ++k) {
      pa[k * 2]     = ntload4(arow0 + base + k * 256);
      pa[k * 2 + 1] = ntload4(arow1 + base + k * 256);
      teb[k] = *(const ushort4*)(jebA + base + k * 256);
      te2[k] = *(const ushort4*)(jeb2A + base + k * 256);
    }
  };

  auto stage_store = [&](int buf) {
#pragma unroll
    for (int r2 = 0; r2 < 2; ++r2) {
      float cr = r2 ? c1 : c0;
#pragma unroll
      for (int k = 0; k < 2; ++k) {
        const i32x4 av = pa[k * 2 + r2];
        const u16* ebp = (const u16*)&teb[k];
        const u16* e2p = (const u16*)&te2[k];
        float wv[4];
#pragma unroll
        for (int e = 0; e < 4; ++e) {
          float ww = fmaxf(bf2f(ebp[e]), cr * bf2f(e2p[e]));
          wv[e] = (av[e] != 0) ? ww : 0.f;
        }
        unsigned p0 = __builtin_amdgcn_perm(__float_as_uint(wv[1]),
                                            __float_as_uint(wv[0]), 0x07060302u);
        unsigned p1 = __builtin_amdgcn_perm(__float_as_uint(wv[3]),
                                            __float_as_uint(wv[2]), 0x07060302u);
        *(uint2*)&wb[buf][(r0 + r2) * WSTRIDE + k * 256 + l * 4] = make_uint2(p0, p1);
      }
    }
  };

  f32x4 acc[8];
#pragma unroll
  for (int nt = 0; nt < 8; ++nt) acc[nt] = f32x4{0.f, 0.f, 0.f, 0.f};
  f32x4 accD = f32x4{0.f, 0.f, 0.f, 0.f};
  u16x8 onesu;
#pragma unroll
  for (int jj = 0; jj < 8; ++jj) onesu[jj] = 0x3F80;
  const bf16x8 ONES = __builtin_bit_cast(bf16x8, onesu);

  auto compute = [&](int p, int buf) {
#pragma unroll
    for (int t = 0; t < 2; ++t) {
      int s = w * 2 + t;  // panel-local kstep, cols s*32..s*32+32
      u16x8 au = *(const u16x8*)&wb[buf][li * WSTRIDE + s * 32 + quad * 8];
      bf16x8 A = __builtin_bit_cast(bf16x8, au);
      const u16* bb = Bsw + (size_t)(p * 16 + s) * 4096 + (size_t)l * 8;
#pragma unroll
      for (int nt = 0; nt < 8; ++nt) {
        bf16x8 B = __builtin_bit_cast(bf16x8, *(const u16x8*)(bb + nt * 512));
        acc[nt] = __builtin_amdgcn_mfma_f32_16x16x32_bf16(A, B, acc[nt], 0, 0, 0);
      }
      accD = __builtin_amdgcn_mfma_f32_16x16x32_bf16(A, ONES, accD, 0, 0, 0);
    }
  };

  // ---- pipelined panel loop ----
  stage_load(0);
  stage_store(0);
  __syncthreads();
  for (int p = 0; p < NP; ++p) {
    if (p + 1 < NP) stage_load(p + 1);
    compute(p, p & 1);
    if (p + 1 < NP) stage_store((p + 1) & 1);
    __syncthreads();
  }

  // ---- reduce across waves ----
  if (li == 0) {
#pragma unroll
    for (int r = 0; r < 4; ++r) atomicAdd(&sden[quad * 4 + r], accD[r]);
  }
#pragma unroll
  for (int nt = 0; nt < 8; ++nt) {
#pragma unroll
    for (int r = 0; r < 4; ++r)
      atomicAdd(&sacc[(quad * 4 + r) * 132 + nt * 16 + li], acc[nt][r]);
  }
  __syncthreads();

  // ---- epilogue: normalize + sigmoid, coalesced float4 store ----
  {
    int r = tid >> 5, c4 = (tid & 31) * 4;
    float4 v = *(const float4*)&sacc[r * 132 + c4];
    float rd = 1.f / sden[r];
    float o[4] = {v.x, v.y, v.z, v.w};
#pragma unroll
    for (int k = 0; k < 4; ++k) {
      float t = o[k] * rd;
      o[k] = 1.f / (1.f + __expf(-t));
    }
    *(float4*)(out + (size_t)(i0 + r) * FOUT + c4) = make_float4(o[0], o[1], o[2], o[3]);
  }
}

extern "C" void kernel_launch(void* const* d_in, const int* in_sizes, int n_in,
                              void* d_out, int out_size, void* d_ws, size_t ws_size,
                              hipStream_t stream) {
  const float* X = (const float*)d_in[0];
  const int* adj = (const int*)d_in[1];
  const float* W = (const float*)d_in[2];
  const float* bias = (const float*)d_in[3];
  const float* S = (const float*)d_in[4];
  float* out = (float*)d_out;

  char* ws = (char*)d_ws;
  u16* Bsw      = (u16*)(ws);                  // 2,097,152 B
  u16* Whi      = (u16*)(ws + 2097152);        //    65,536 B
  u16* Wlo      = (u16*)(ws + 2162688);        //    65,536 B
  float* cexpA  = (float*)(ws + 2228224);      //    32,768 B
  u16* jebA     = (u16*)(ws + 2260992);        //    16,384 B
  u16* jeb2A    = (u16*)(ws + 2277376);        //    16,384 B
  float* diagW  = (float*)(ws + 2293760);      //    32,768 B -> end 2,326,528

  hipLaunchKernelGGL(k_splitw, dim3(128), dim3(256), 0, stream, W, Whi, Wlo);
  hipLaunchKernelGGL(k_xp, dim3(512), dim3(256), 0, stream, X, Whi, Wlo, bias, S, adj,
                     Bsw, cexpA, jebA, jeb2A, diagW);
  hipLaunchKernelGGL(k_gat, dim3(512), dim3(512), 0, stream, adj, Bsw, cexpA,
                     jebA, jeb2A, diagW, out);
}